// Round 3
// baseline (2005.277 us; speedup 1.0000x reference)
//
#include <hip/hip_runtime.h>
#include <cmath>

// Problem dims (fixed by the reference)
constexpr int kB = 32, kH = 48, kT = 24, kS = 256, kA = 64, kR = 8, kF = 1024;
constexpr int kSEQ = kH + 1;           // 49 = history + present step
constexpr float kEPS = 1e-5f;

// Persistent-kernel config: 128 blocks x 512 thr (8 waves).
// Blocks 0..63: layer-0 f-tiles (16 cols). Blocks 64..127: layer-1.
constexpr int G  = 128;
constexpr int BT = 512;

// Tree barrier: 8 logical groups x 16 blocks, all counters at LLC.
constexpr int GRPS = 8;
constexpr int GMEM = 16;

typedef __attribute__((ext_vector_type(8))) short short8;   // 8 x bf16
typedef __attribute__((ext_vector_type(4))) float f32x4;

union U4S8 { uint4 u; short8 s; };

__device__ __forceinline__ unsigned bfbits(float x) {  // RNE f32->bf16
  unsigned u = __float_as_uint(x);
  return (u + 0x7fffu + ((u >> 16) & 1u)) >> 16;
}
__device__ __forceinline__ float bf_lo(unsigned u) { return __uint_as_float(u << 16); }
__device__ __forceinline__ float bf_hi(unsigned u) { return __uint_as_float(u & 0xffff0000u); }
__device__ __forceinline__ float bf2f(unsigned short h) {
  return __uint_as_float(((unsigned)h) << 16);
}
__device__ __forceinline__ float gelu_f(float x) {
  return 0.5f * x * (1.0f + erff(x * 0.7071067811865476f));
}
__device__ __forceinline__ float sigmoid_f(float x) {
  return 1.0f / (1.0f + expf(-x));
}
// dot of 8 bf16 weights with 8 bf16 activations (both packed)
__device__ __forceinline__ float dot8bb(const unsigned short* w, const unsigned short* y) {
  uint4 a = *(const uint4*)w; uint4 b = *(const uint4*)y;
  float r = 0.f;
  r += bf_lo(a.x)*bf_lo(b.x); r += bf_hi(a.x)*bf_hi(b.x);
  r += bf_lo(a.y)*bf_lo(b.y); r += bf_hi(a.y)*bf_hi(b.y);
  r += bf_lo(a.z)*bf_lo(b.z); r += bf_hi(a.z)*bf_hi(b.z);
  r += bf_lo(a.w)*bf_lo(b.w); r += bf_hi(a.w)*bf_hi(b.w);
  return r;
}

// sc1 (LLC write-through) stores: visible to all XCDs.
__device__ __forceinline__ void coh_st(unsigned* p, unsigned v) {
  __hip_atomic_store(p, v, __ATOMIC_RELAXED, __HIP_MEMORY_SCOPE_AGENT);
}
__device__ __forceinline__ void coh_stf(float* p, float v) {
  __hip_atomic_store(p, v, __ATOMIC_RELAXED, __HIP_MEMORY_SCOPE_AGENT);
}

// Pinned LLC poll load: bypass L1+L2, explicit drain.
__device__ __forceinline__ unsigned poll_ld(const unsigned* p) {
  unsigned v;
  asm volatile("global_load_dword %0, %1, off sc0 sc1\n\t"
               "s_waitcnt vmcnt(0)"
               : "=v"(v) : "v"(p) : "memory");
  return v;
}

// ---------------- grid sync: two-level LLC tree (R10, measured win) --------
__device__ __forceinline__ void sync_grid(unsigned* bar, int grp, int& t) {
  __syncthreads();
  if (threadIdx.x == 0) {
    const unsigned tt = (unsigned)t;
    unsigned* garr = bar + grp * 32;
    unsigned* root = bar + GRPS * 32;
    unsigned* grel = bar + (GRPS + 1) * 32 + grp * 32;
    const unsigned old = __hip_atomic_fetch_add(
        garr, 1u, __ATOMIC_RELAXED, __HIP_MEMORY_SCOPE_AGENT);
    if (old == (unsigned)GMEM * tt - 1u) {        // last local arriver
      const unsigned rold = __hip_atomic_fetch_add(
          root, 1u, __ATOMIC_RELAXED, __HIP_MEMORY_SCOPE_AGENT);
      if (rold != (unsigned)GRPS * tt - 1u) {     // not globally last: poll
        while (poll_ld(root) < (unsigned)GRPS * tt) { }
      }
      __hip_atomic_fetch_add(grel, 1u, __ATOMIC_RELAXED,
                             __HIP_MEMORY_SCOPE_AGENT);
    } else {
      while (poll_ld(grel) < tt) { }
    }
  }
  __syncthreads();
  t++;
}

// ---------------- GRU core: MFMA + combine + gated store -------------------
// Ax/Ah: A-fragments (x and h). Block owns 16 f-cols; wave wv = k-slice.
__device__ __forceinline__ void gru_core(
    const short8 (&Ax)[2][4], const short8 (&Ah)[2][4],
    unsigned short* __restrict__ hdst,
    const short8 (&Bf)[2][3][4],
    float bR, float bZ, float bIN, float bHN,
    float& h_old, float* part, int fb)
{
  const int tid = threadIdx.x;
  const int wv = tid >> 6, l = tid & 63, q = l >> 4, c = l & 15;

  f32x4 C[4][2];
  #pragma unroll
  for (int s = 0; s < 4; s++)
    #pragma unroll
    for (int mt = 0; mt < 2; mt++)
      C[s][mt] = (f32x4){0.f, 0.f, 0.f, 0.f};

  #pragma unroll
  for (int mt = 0; mt < 2; mt++)
    #pragma unroll
    for (int j = 0; j < 4; j++) {
      C[0][mt] = __builtin_amdgcn_mfma_f32_16x16x32_bf16(Ax[mt][j], Bf[0][0][j], C[0][mt], 0, 0, 0);
      C[0][mt] = __builtin_amdgcn_mfma_f32_16x16x32_bf16(Ah[mt][j], Bf[1][0][j], C[0][mt], 0, 0, 0);
      C[1][mt] = __builtin_amdgcn_mfma_f32_16x16x32_bf16(Ax[mt][j], Bf[0][1][j], C[1][mt], 0, 0, 0);
      C[1][mt] = __builtin_amdgcn_mfma_f32_16x16x32_bf16(Ah[mt][j], Bf[1][1][j], C[1][mt], 0, 0, 0);
      C[2][mt] = __builtin_amdgcn_mfma_f32_16x16x32_bf16(Ax[mt][j], Bf[0][2][j], C[2][mt], 0, 0, 0);
      C[3][mt] = __builtin_amdgcn_mfma_f32_16x16x32_bf16(Ah[mt][j], Bf[1][2][j], C[3][mt], 0, 0, 0);
    }

  // k-slice partials -> LDS (swizzled: 2-way/bank over 64 lanes = free).
  const int perm = (wv + l + (l >> 3)) & 7;
  #pragma unroll
  for (int s = 0; s < 4; s++)
    #pragma unroll
    for (int mt = 0; mt < 2; mt++)
      #pragma unroll
      for (int r = 0; r < 4; r++)
        part[((s*2 + mt)*4 + r)*512 + l*8 + perm] = C[s][mt][r];
  __syncthreads();

  // combine: wave wv -> (mtile = wv&1, reg = wv>>1); lane -> one (b,f)
  const int mt_c = wv & 1, rg = wv >> 1;
  const int b_own = mt_c*16 + q*4 + rg;
  float S[4];
  #pragma unroll
  for (int s = 0; s < 4; s++) {
    const float* pp = part + ((s*2 + mt_c)*4 + rg)*512 + l*8;
    f32x4 a = *(const f32x4*)pp;
    f32x4 b = *(const f32x4*)(pp + 4);
    S[s] = ((a[0]+a[1]) + (a[2]+a[3])) + ((b[0]+b[1]) + (b[2]+b[3]));
  }
  float rr = sigmoid_f(S[0] + bR);
  float zz = sigmoid_f(S[1] + bZ);
  float nn = tanhf(S[2] + bIN + rr * (S[3] + bHN));
  float hn = (1.f - zz)*nn + zz*h_old;
  h_old = hn;
  float nb = __shfl_xor(hn, 1);
  if (!(c & 1)) {
    unsigned pk = bfbits(hn) | (bfbits(nb) << 16);
    coh_st((unsigned*)(hdst + b_own*1024 + fb*16 + c), pk);
  }
  __syncthreads();   // protect smem reuse by next stage
}

// layer_stage: load x/h A-frags from global (fresh rotation buffers) + core.
__device__ __forceinline__ void layer_stage(
    const unsigned short* __restrict__ xsrc,
    const unsigned short* __restrict__ hsrc,
    unsigned short* __restrict__ hdst,
    const short8 (&Bf)[2][3][4],
    float bR, float bZ, float bIN, float bHN,
    float& h_old, float* part, int fb)
{
  const int tid = threadIdx.x;
  const int wv = tid >> 6, l = tid & 63, q = l >> 4, c = l & 15;
  short8 Ax[2][4], Ah[2][4];
  #pragma unroll
  for (int mt = 0; mt < 2; mt++)
    #pragma unroll
    for (int j = 0; j < 4; j++) {
      const int off = (mt*16 + c)*1024 + wv*128 + j*32 + q*8;
      Ax[mt][j] = *(const short8*)(xsrc + off);
      Ah[mt][j] = *(const short8*)(hsrc + off);
    }
  gru_core(Ax, Ah, hdst, Bf, bR, bZ, bIN, bHN, h_old, part, fb);
}

// ---------------- U-stage: u = y @ Wc^T + bc (R11) -------------------------
// 64 blocks (L0 set). Block fb computes u[32][fb*16..+16] via MFMA, writes
// u (f32, sc1) + per-block LN partials (sum, sumsq per batch).
__device__ __forceinline__ void u_stage(
    const unsigned short* __restrict__ ysrc,   // [32][1024] bf16
    const unsigned short* __restrict__ Wc_bf,  // [1024][1024] bf16
    const float* __restrict__ bc,              // [1024]
    float* __restrict__ ubuf,                  // [32][1024] f32
    float* __restrict__ upart,                 // [32][64][2] f32
    float* part, int fb)
{
  const int tid = threadIdx.x;
  const int wv = tid >> 6, l = tid & 63, q = l >> 4, c = l & 15;
  short8 Ay[2][4], Bu[4];
  #pragma unroll
  for (int j = 0; j < 4; j++) {
    const int koff = wv*128 + j*32 + q*8;
    Ay[0][j] = *(const short8*)(ysrc + c*1024 + koff);
    Ay[1][j] = *(const short8*)(ysrc + (16 + c)*1024 + koff);
    Bu[j]    = *(const short8*)(Wc_bf + (size_t)(fb*16 + c)*1024 + koff);
  }
  f32x4 C[2];
  C[0] = (f32x4){0.f,0.f,0.f,0.f}; C[1] = (f32x4){0.f,0.f,0.f,0.f};
  #pragma unroll
  for (int j = 0; j < 4; j++) {
    C[0] = __builtin_amdgcn_mfma_f32_16x16x32_bf16(Ay[0][j], Bu[j], C[0], 0, 0, 0);
    C[1] = __builtin_amdgcn_mfma_f32_16x16x32_bf16(Ay[1][j], Bu[j], C[1], 0, 0, 0);
  }
  const int perm = (wv + l + (l >> 3)) & 7;
  #pragma unroll
  for (int mt = 0; mt < 2; mt++)
    #pragma unroll
    for (int r = 0; r < 4; r++)
      part[(mt*4 + r)*512 + l*8 + perm] = C[mt][r];
  __syncthreads();
  const int mt_c = wv & 1, rg = wv >> 1;
  const int b_own = mt_c*16 + q*4 + rg;
  const float* pp = part + (mt_c*4 + rg)*512 + l*8;
  f32x4 a = *(const f32x4*)pp;
  f32x4 b2 = *(const f32x4*)(pp + 4);
  float u = ((a[0]+a[1]) + (a[2]+a[3])) + ((b2[0]+b2[1]) + (b2[2]+b2[3]));
  u += bc[fb*16 + c];
  coh_stf(ubuf + b_own*1024 + fb*16 + c, u);
  // per-block LN partials over the 16 cols (c = low 4 lane bits)
  float s1 = u, s2 = u*u;
  #pragma unroll
  for (int m = 1; m < 16; m <<= 1) {
    s1 += __shfl_xor(s1, m); s2 += __shfl_xor(s2, m);
  }
  if (c == 0) {
    coh_stf(upart + (b_own*64 + fb)*2 + 0, s1);
    coh_stf(upart + (b_own*64 + fb)*2 + 1, s2);
  }
  __syncthreads();
}

// ---------------- L0 fused: stats-reduce + normalize+gelu + GRU ------------
__device__ __forceinline__ void layer0_fused(
    const float* __restrict__ ubuf, const float* __restrict__ upart,
    const unsigned short* __restrict__ fa_t,   // [32][1024] bf16 (fa[t+1])
    const float* __restrict__ g_sn, const float* __restrict__ b_sn,
    const unsigned short* __restrict__ hsrc,
    unsigned short* __restrict__ hdst,
    const short8 (&Bf)[2][3][4],
    float bR, float bZ, float bIN, float bHN,
    float& h_old, float* part, float* stats, int fb)
{
  const int tid = threadIdx.x;
  const int wv = tid >> 6, l = tid & 63, q = l >> 4, c = l & 15;

  // 1) LN stats: 16 threads per batch reduce the 64 block-partials
  {
    const int b = tid >> 4, i = tid & 15;
    const float* pp = upart + b*128 + i*8;    // 4 (s1,s2) pairs
    f32x4 A = *(const f32x4*)pp;
    f32x4 Bv = *(const f32x4*)(pp + 4);
    float s1 = (A[0] + A[2]) + (Bv[0] + Bv[2]);
    float s2 = (A[1] + A[3]) + (Bv[1] + Bv[3]);
    #pragma unroll
    for (int m = 1; m < 16; m <<= 1) {
      s1 += __shfl_xor(s1, m); s2 += __shfl_xor(s2, m);
    }
    if (i == 0) {
      const float mean = s1 * (1.0f/kF);
      const float var  = s2 * (1.0f/kF) - mean*mean;
      stats[b*2]     = mean;
      stats[b*2 + 1] = rsqrtf(var + kEPS);
    }
  }
  __syncthreads();

  // 2) load u k-slices, x = gelu(LN(u)*g+b + fa), pack bf16 A-frags
  short8 Ax[2][4], Ah[2][4];
  #pragma unroll
  for (int mt = 0; mt < 2; mt++) {
    const int b = mt*16 + c;
    const float mean = stats[b*2], inv = stats[b*2 + 1];
    #pragma unroll
    for (int j = 0; j < 4; j++) {
      const int k0 = wv*128 + j*32 + q*8;
      f32x4 u0 = *(const f32x4*)(ubuf + b*1024 + k0);
      f32x4 u1 = *(const f32x4*)(ubuf + b*1024 + k0 + 4);
      f32x4 g0 = *(const f32x4*)(g_sn + k0);
      f32x4 g1 = *(const f32x4*)(g_sn + k0 + 4);
      f32x4 bb0 = *(const f32x4*)(b_sn + k0);
      f32x4 bb1 = *(const f32x4*)(b_sn + k0 + 4);
      uint4 fv = *(const uint4*)(fa_t + b*1024 + k0);
      float x0 = gelu_f((u0[0]-mean)*inv*g0[0] + bb0[0] + bf_lo(fv.x));
      float x1 = gelu_f((u0[1]-mean)*inv*g0[1] + bb0[1] + bf_hi(fv.x));
      float x2 = gelu_f((u0[2]-mean)*inv*g0[2] + bb0[2] + bf_lo(fv.y));
      float x3 = gelu_f((u0[3]-mean)*inv*g0[3] + bb0[3] + bf_hi(fv.y));
      float x4 = gelu_f((u1[0]-mean)*inv*g1[0] + bb1[0] + bf_lo(fv.z));
      float x5 = gelu_f((u1[1]-mean)*inv*g1[1] + bb1[1] + bf_hi(fv.z));
      float x6 = gelu_f((u1[2]-mean)*inv*g1[2] + bb1[2] + bf_lo(fv.w));
      float x7 = gelu_f((u1[3]-mean)*inv*g1[3] + bb1[3] + bf_hi(fv.w));
      U4S8 u;
      u.u.x = bfbits(x0) | (bfbits(x1) << 16);
      u.u.y = bfbits(x2) | (bfbits(x3) << 16);
      u.u.z = bfbits(x4) | (bfbits(x5) << 16);
      u.u.w = bfbits(x6) | (bfbits(x7) << 16);
      Ax[mt][j] = u.s;
      const int off = b*1024 + k0;
      Ah[mt][j] = *(const short8*)(hsrc + off);
    }
  }
  gru_core(Ax, Ah, hdst, Bf, bR, bZ, bIN, bHN, h_old, part, fb);
}

// ---------------- persistent kernel ----------------------------------------
__global__ __launch_bounds__(BT, 2) void gru_persist(
    const float* __restrict__ gru_Wi, const float* __restrict__ gru_Wh,
    const float* __restrict__ gru_bi, const float* __restrict__ gru_bh,
    const unsigned short* __restrict__ Ws_bf, const float* __restrict__ b_sout,
    const unsigned short* __restrict__ Wr_bf, const float* __restrict__ b_reward,
    const unsigned short* __restrict__ Wc_bf, const float* __restrict__ bc,
    const float* __restrict__ g_sn, const float* __restrict__ b_sn,
    const unsigned short* __restrict__ seq0_bf, const unsigned short* __restrict__ fa_bf,
    unsigned short* h0pool, unsigned short* h1pool,
    float* ubpool, float* uppool,
    unsigned* cnt,
    float* __restrict__ out_r, float* __restrict__ out_s)
{
  __shared__ float part[32 * 512];   // 64 KB, aliased by all stages
  __shared__ float stats[64];        // per-batch (mean, inv) for L0-fused
  const int tid = threadIdx.x;
  const int blk = blockIdx.x;
  const int wv = tid >> 6, l = tid & 63, q = l >> 4, c = l & 15;
  const bool isL1 = (blk >= 64);
  const int fb = blk & 63;
  const int grp = blk >> 4;
  const int lay = isL1 ? 1 : 0;
  const size_t BF = (size_t)kB * kF;

  // ---- preamble: resident B-fragments (bf16) + gate biases ----
  short8 Bf[2][3][4];
  {
    const size_t WLL = (size_t)3 * kF * kF;
    const float* Wm[2] = { gru_Wi + lay*WLL, gru_Wh + lay*WLL };
    #pragma unroll
    for (int m = 0; m < 2; m++)
      #pragma unroll
      for (int g = 0; g < 3; g++)
        #pragma unroll
        for (int j = 0; j < 4; j++) {
          const float* p = Wm[m] + ((size_t)(g*kF + fb*16 + c))*kF + wv*128 + j*32 + q*8;
          float4 a = *(const float4*)p;
          float4 b = *(const float4*)(p + 4);
          U4S8 u;
          u.u.x = bfbits(a.x) | (bfbits(a.y) << 16);
          u.u.y = bfbits(a.z) | (bfbits(a.w) << 16);
          u.u.z = bfbits(b.x) | (bfbits(b.y) << 16);
          u.u.w = bfbits(b.z) | (bfbits(b.w) << 16);
          Bf[m][g][j] = u.s;
        }
  }
  const int f = fb*16 + c;
  const float* bi = gru_bi + lay*3*kF;
  const float* bh = gru_bh + lay*3*kF;
  const float bR  = bi[f] + bh[f];
  const float bZ  = bi[kF + f] + bh[kF + f];
  const float bIN = bi[2*kF + f];
  const float bHN = bh[2*kF + f];

  float h_old = 0.f;
  int tg = 1;

  #define H0P(i) (h0pool + (size_t)(i)*BF)
  #define H1P(i) (h1pool + (size_t)(i)*BF)
  #define UBP(i) (ubpool + (size_t)(i)*BF)
  #define UPP(i) (uppool + (size_t)(i)*4096)

  // ---- history wavefront: superstage s = 0..49 ----
  for (int s = 0; s < 50; s++) {
    if (!isL1) {
      if (s < 49)
        layer_stage(seq0_bf + (size_t)s*BF, H0P(s), H0P(s+1),
                    Bf, bR, bZ, bIN, bHN, h_old, part, fb);
    } else {
      if (s >= 1)
        layer_stage(H0P(s), H1P(s-1), H1P(s),
                    Bf, bR, bZ, bIN, bHN, h_old, part, fb);
    }
    sync_grid(cnt, grp, tg);
  }

  // ---- future: per t (0..22): U -> L0(fused x) -> L1 ----
  // U(t):  u = h1p(49+t) @ Wc^T + bc  (x for GRU-step t+1, pre-LN)
  // L0(t): x = gelu(LN(u)*g+b + fa[t+1]); h0p(49+t) -> h0p(50+t)
  // L1(t): x = h0p(50+t), h1p(49+t) -> h1p(50+t)
  for (int t = 0; t < kT - 1; t++) {
    if (!isL1)
      u_stage(H1P(49+t), Wc_bf, bc, UBP(t), UPP(t), part, fb);
    sync_grid(cnt, grp, tg);
    if (!isL1)
      layer0_fused(UBP(t), UPP(t), fa_bf + (size_t)(t+1)*BF, g_sn, b_sn,
                   H0P(49+t), H0P(50+t), Bf, bR, bZ, bIN, bHN,
                   h_old, part, stats, fb);
    sync_grid(cnt, grp, tg);
    if (isL1)
      layer_stage(H0P(50+t), H1P(49+t), H1P(50+t),
                  Bf, bR, bZ, bIN, bHN, h_old, part, fb);
    sync_grid(cnt, grp, tg);
  }

  // ---- endgame: all heads in parallel, no barriers (y_t all resident) ----
  // blocks 0..95: out_s tiles (t = blk>>2, 64 cols = (blk&3)*64)
  // blocks 96..119: out_r (t = blk-96)
  if (blk < 96) {
    const int t = blk >> 2, jq = blk & 3;
    const unsigned short* y = H1P(49 + t);
    short8 Ay[2][4], Bs[4][4];
    #pragma unroll
    for (int j = 0; j < 4; j++) {
      const int koff = wv*128 + j*32 + q*8;
      Ay[0][j] = *(const short8*)(y + c*1024 + koff);
      Ay[1][j] = *(const short8*)(y + (16 + c)*1024 + koff);
      #pragma unroll
      for (int g = 0; g < 4; g++)
        Bs[g][j] = *(const short8*)(Ws_bf + (size_t)(jq*64 + g*16 + c)*1024 + koff);
    }
    f32x4 C[4][2];
    #pragma unroll
    for (int g = 0; g < 4; g++) {
      C[g][0] = (f32x4){0.f,0.f,0.f,0.f};
      C[g][1] = (f32x4){0.f,0.f,0.f,0.f};
    }
    #pragma unroll
    for (int j = 0; j < 4; j++)
      #pragma unroll
      for (int g = 0; g < 4; g++) {
        C[g][0] = __builtin_amdgcn_mfma_f32_16x16x32_bf16(Ay[0][j], Bs[g][j], C[g][0], 0, 0, 0);
        C[g][1] = __builtin_amdgcn_mfma_f32_16x16x32_bf16(Ay[1][j], Bs[g][j], C[g][1], 0, 0, 0);
      }
    const int perm = (wv + l + (l >> 3)) & 7;
    #pragma unroll
    for (int g = 0; g < 4; g++)
      #pragma unroll
      for (int mt = 0; mt < 2; mt++)
        #pragma unroll
        for (int r = 0; r < 4; r++)
          part[((g*2 + mt)*4 + r)*512 + l*8 + perm] = C[g][mt][r];
    __syncthreads();
    const int mt_c = wv & 1, rg = wv >> 1;
    const int b_own = mt_c*16 + q*4 + rg;
    #pragma unroll
    for (int g = 0; g < 4; g++) {
      const float* pp = part + ((g*2 + mt_c)*4 + rg)*512 + l*8;
      f32x4 a = *(const f32x4*)pp;
      f32x4 b2 = *(const f32x4*)(pp + 4);
      float S = ((a[0]+a[1]) + (a[2]+a[3])) + ((b2[0]+b2[1]) + (b2[2]+b2[3]));
      const int col = jq*64 + g*16 + c;
      out_s[((size_t)b_own*kT + t)*kS + col] = S + b_sout[col];
    }
  } else if (blk < 96 + kT) {
    const int t = blk - 96;
    const unsigned short* y = H1P(49 + t);
    const int idx = tid >> 1, half = tid & 1;
    const int b = idx >> 3, j = idx & 7;
    const unsigned short* wr = Wr_bf + j*1024 + half*512;
    const unsigned short* yp = y + b*1024 + half*512;
    float acc = 0.f;
    #pragma unroll 8
    for (int k = 0; k < 512; k += 8) acc += dot8bb(wr + k, yp + k);
    acc += __shfl_xor(acc, 1);
    if (half == 0)
      out_r[((size_t)b*kT + t)*kR + j] = tanhf(acc + b_reward[j]);
  }
  #undef H0P
  #undef H1P
  #undef UBP
  #undef UPP
}

// ---------------- setup: convert head weights to bf16 ----------------------
__global__ __launch_bounds__(512) void convert_weights(
    const float* __restrict__ ws, unsigned short* __restrict__ o1,
    const float* __restrict__ wr, unsigned short* __restrict__ o3)
{
  const int stride = gridDim.x * blockDim.x;
  const int i0 = blockIdx.x * blockDim.x + threadIdx.x;
  for (int i = i0; i < kS*kF; i += stride) o1[i] = (unsigned short)bfbits(ws[i]);
  for (int i = i0; i < kR*kF; i += stride) o3[i] = (unsigned short)bfbits(wr[i]);
}

// ---------------- setup: Wc = W_state @ W_sout (f32 accum -> bf16) ---------
// bc = b_state + W_state @ b_sout. 256 blocks x 256 thr; block = 4 rows.
__global__ __launch_bounds__(256) void wc_kernel(
    const float* __restrict__ W_state,  // [1024][256]
    const float* __restrict__ W_sout,   // [256][1024]
    const float* __restrict__ b_state, const float* __restrict__ b_sout,
    unsigned short* __restrict__ Wc_bf, float* __restrict__ bc)
{
  __shared__ float wrow[4][256];
  __shared__ float bso[256];
  const int blk = blockIdx.x;
  const int tid = threadIdx.x;
  const int i0 = blk * 4;
  #pragma unroll
  for (int rr = 0; rr < 4; rr++)
    wrow[rr][tid] = W_state[(size_t)(i0 + rr)*256 + tid];
  bso[tid] = b_sout[tid];
  __syncthreads();
  for (int qq = 0; qq < 4; qq++) {
    const int col = qq*256 + tid;
    float a0 = 0.f, a1 = 0.f, a2 = 0.f, a3 = 0.f;
    for (int j = 0; j < 256; j++) {
      const float w = W_sout[(size_t)j*1024 + col];
      a0 += wrow[0][j]*w; a1 += wrow[1][j]*w;
      a2 += wrow[2][j]*w; a3 += wrow[3][j]*w;
    }
    Wc_bf[(size_t)(i0+0)*1024 + col] = (unsigned short)bfbits(a0);
    Wc_bf[(size_t)(i0+1)*1024 + col] = (unsigned short)bfbits(a1);
    Wc_bf[(size_t)(i0+2)*1024 + col] = (unsigned short)bfbits(a2);
    Wc_bf[(size_t)(i0+3)*1024 + col] = (unsigned short)bfbits(a3);
  }
  if (tid < 4) {
    float a = b_state[i0 + tid];
    for (int j = 0; j < 256; j++) a += wrow[tid][j]*bso[j];
    bc[i0 + tid] = a;
  }
}

// ---------------- encoder: fa_bf[t][b][f] = bf16(LN(future_a@Wa^T+ba)*g+b) -
__global__ __launch_bounds__(256) void encode_fa_kernel(
    const float* __restrict__ future_a,
    const float* __restrict__ W_action, const float* __restrict__ b_action,
    const float* __restrict__ g_an, const float* __restrict__ b_an,
    unsigned short* __restrict__ fa_bf)
{
  __shared__ __align__(16) float arow[kA];
  __shared__ float red1[256], red2[256];
  const int bid = blockIdx.x;
  const int b = bid & (kB - 1);
  const int t = bid >> 5;
  const int tid = threadIdx.x;
  if (tid < kA) arow[tid] = future_a[((size_t)b*kT + t)*kA + tid];
  __syncthreads();
  float v[4]; float s1 = 0.f, s2 = 0.f;
  #pragma unroll
  for (int j = 0; j < 4; j++) {
    const int ff = tid + j*256;
    const float* wr = W_action + (size_t)ff*kA;
    float acc = b_action[ff];
    for (int k = 0; k < kA; k += 4) {
      float4 w  = *(const float4*)(wr + k);
      float4 xv = *(const float4*)(arow + k);
      acc += xv.x*w.x + xv.y*w.y + xv.z*w.z + xv.w*w.w;
    }
    v[j] = acc; s1 += acc; s2 += acc*acc;
  }
  red1[tid] = s1; red2[tid] = s2;
  __syncthreads();
  for (int off = 128; off > 0; off >>= 1) {
    if (tid < off) { red1[tid] += red1[tid+off]; red2[tid] += red2[tid+off]; }
    __syncthreads();
  }
  const float m = red1[0] * (1.0f/kF);
  const float va = red2[0] * (1.0f/kF) - m*m;
  const float inv = rsqrtf(va + kEPS);
  #pragma unroll
  for (int j = 0; j < 4; j++) {
    const int ff = tid + j*256;
    fa_bf[((size_t)t*kB + b)*kF + ff] =
        (unsigned short)bfbits((v[j] - m)*inv*g_an[ff] + b_an[ff]);
  }
}

// ---------------- encoder: seq0_bf = bf16(gelu(LN_s + LN_a)) ---------------
__global__ __launch_bounds__(256) void encode_seq0_kernel(
    const float* __restrict__ history_s, const float* __restrict__ history_a,
    const float* __restrict__ present_s,
    const float* __restrict__ W_state, const float* __restrict__ b_state,
    const float* __restrict__ g_sn, const float* __restrict__ b_sn,
    const float* __restrict__ W_action, const float* __restrict__ b_action,
    const float* __restrict__ g_an, const float* __restrict__ b_an,
    const unsigned short* __restrict__ fa_bf, unsigned short* __restrict__ seq0_bf)
{
  __shared__ __align__(16) float srow[kS];
  __shared__ __align__(16) float arow[kA];
  __shared__ float red1[256], red2[256];
  const int bid = blockIdx.x;
  const int b = bid & (kB - 1);
  const int t = bid >> 5;                 // 0..48
  const int tid = threadIdx.x;
  const bool hist = (t < kH);
  const float* sp = hist ? (history_s + ((size_t)b*kH + t)*kS)
                         : (present_s + (size_t)b*kS);
  srow[tid] = sp[tid];
  if (hist && tid < kA) arow[tid] = history_a[((size_t)b*kH + t)*kA + tid];
  __syncthreads();

  float u[4]; float s1 = 0.f, s2 = 0.f;
  #pragma unroll
  for (int j = 0; j < 4; j++) {
    const int ff = tid + j*256;
    const float* wr = W_state + (size_t)ff*kS;
    float acc = b_state[ff];
    for (int k = 0; k < kS; k += 4) {
      float4 w  = *(const float4*)(wr + k);
      float4 xv = *(const float4*)(srow + k);
      acc += xv.x*w.x + xv.y*w.y + xv.z*w.z + xv.w*w.w;
    }
    u[j] = acc; s1 += acc; s2 += acc*acc;
  }
  red1[tid] = s1; red2[tid] = s2;
  __syncthreads();
  for (int off = 128; off > 0; off >>= 1) {
    if (tid < off) { red1[tid] += red1[tid+off]; red2[tid] += red2[tid+off]; }
    __syncthreads();
  }
  const float mu = red1[0] * (1.0f/kF);
  const float vu = red2[0] * (1.0f/kF) - mu*mu;
  const float iu = rsqrtf(vu + kEPS);
  __syncthreads();

  if (hist) {
    float v[4]; s1 = 0.f; s2 = 0.f;
    #pragma unroll
    for (int j = 0; j < 4; j++) {
      const int ff = tid + j*256;
      const float* wr = W_action + (size_t)ff*kA;
      float acc = b_action[ff];
      for (int k = 0; k < kA; k += 4) {
        float4 w  = *(const float4*)(wr + k);
        float4 xv = *(const float4*)(arow + k);
        acc += xv.x*w.x + xv.y*w.y + xv.z*w.z + xv.w*w.w;
      }
      v[j] = acc; s1 += acc; s2 += acc*acc;
    }
    red1[tid] = s1; red2[tid] = s2;
    __syncthreads();
    for (int off = 128; off > 0; off >>= 1) {
      if (tid < off) { red1[tid] += red1[tid+off]; red2[tid] += red2[tid+off]; }
      __syncthreads();
    }
    const float mv = red1[0] * (1.0f/kF);
    const float vv = red2[0] * (1.0f/kF) - mv*mv;
    const float iv = rsqrtf(vv + kEPS);
    #pragma unroll
    for (int j = 0; j < 4; j++) {
      const int ff = tid + j*256;
      const float un = (u[j] - mu)*iu*g_sn[ff] + b_sn[ff];
      const float vn = (v[j] - mv)*iv*g_an[ff] + b_an[ff];
      seq0_bf[((size_t)t*kB + b)*kF + ff] = (unsigned short)bfbits(gelu_f(un + vn));
    }
  } else {
    #pragma unroll
    for (int j = 0; j < 4; j++) {
      const int ff = tid + j*256;
      const float un = (u[j] - mu)*iu*g_sn[ff] + b_sn[ff];
      seq0_bf[((size_t)t*kB + b)*kF + ff] =
          (unsigned short)bfbits(gelu_f(un + bf2f(fa_bf[(size_t)b*kF + ff])));
    }
  }
}

// ---------------- host launcher -------------------------------------------
extern "C" void kernel_launch(void* const* d_in, const int* in_sizes, int n_in,
                              void* d_out, int out_size, void* d_ws, size_t ws_size,
                              hipStream_t stream) {
  (void)in_sizes; (void)n_in; (void)out_size;
  const float* history_s = (const float*)d_in[0];
  const float* history_a = (const float*)d_in[1];
  const float* present_s = (const float*)d_in[2];
  /* d_in[3] future_s: unused by the reference forward */
  const float* future_a  = (const float*)d_in[4];
  const float* W_state   = (const float*)d_in[5];
  const float* b_state   = (const float*)d_in[6];
  const float* g_sn      = (const float*)d_in[7];
  const float* b_sn      = (const float*)d_in[8];
  const float* W_action  = (const float*)d_in[9];
  const float* b_action  = (const float*)d_in[10];
  const float* g_an      = (const float*)d_in[11];
  const float* b_an      = (const float*)d_in[12];
  const float* gru_Wi    = (const float*)d_in[13];
  const float* gru_Wh    = (const float*)d_in[14];
  const float* gru_bi    = (const float*)d_in[15];
  const float* gru_bh    = (const float*)d_in[16];
  const float* W_reward  = (const float*)d_in[17];
  const float* b_reward  = (const float*)d_in[18];
  const float* W_sout    = (const float*)d_in[19];
  const float* b_sout    = (const float*)d_in[20];

  // workspace layout (bytes, 16-aligned)
  char* ws = (char*)d_ws;
  unsigned short* seq0_bf = (unsigned short*)(ws + 0);            //  3,211,264
  unsigned short* fa_bf   = (unsigned short*)(ws + 3211264);      //  1,572,864
  unsigned short* Ws_bf   = (unsigned short*)(ws + 4784128);      //    524,288
  unsigned short* Wr_bf   = (unsigned short*)(ws + 5308416);      //     16,384
  unsigned short* Wc_bf   = (unsigned short*)(ws + 5324800);      //  2,097,152
  float*          bc      = (float*)        (ws + 7421952);       //      4,096
  unsigned short* h0pool  = (unsigned short*)(ws + 7426048);      //  4,784,128 (73 x 64K)
  unsigned short* h1pool  = (unsigned short*)(ws + 12210176);     //  4,784,128 (73 x 64K)
  float*          ubpool  = (float*)        (ws + 16994304);      //  3,014,656 (23 x 128K)
  float*          uppool  = (float*)        (ws + 20008960);      //    376,832 (23 x 16K)
  unsigned*       cnt     = (unsigned*)     (ws + 20385792);      //      2,304
  const size_t need = 20388096;
  if (ws_size < need) return;

  hipMemsetAsync((void*)h0pool, 0, 65536, stream);
  hipMemsetAsync((void*)h1pool, 0, 65536, stream);
  hipMemsetAsync((void*)cnt, 0, 2304, stream);

  float* out_r = (float*)d_out;                          // [B][T][R]
  float* out_s = out_r + (size_t)kB*kT*kR;               // [B][T][S]

  hipLaunchKernelGGL(convert_weights, dim3(256), dim3(512), 0, stream,
                     W_sout, Ws_bf, W_reward, Wr_bf);
  hipLaunchKernelGGL(wc_kernel, dim3(256), dim3(256), 0, stream,
                     W_state, W_sout, b_state, b_sout, Wc_bf, bc);
  hipLaunchKernelGGL(encode_fa_kernel, dim3(kT*kB), dim3(256), 0, stream,
                     future_a, W_action, b_action, g_an, b_an, fa_bf);
  hipLaunchKernelGGL(encode_seq0_kernel, dim3(kSEQ*kB), dim3(256), 0, stream,
                     history_s, history_a, present_s,
                     W_state, b_state, g_sn, b_sn,
                     W_action, b_action, g_an, b_an, fa_bf, seq0_bf);
  hipLaunchKernelGGL(gru_persist, dim3(G), dim3(BT), 0, stream,
                     gru_Wi, gru_Wh, gru_bi, gru_bh,
                     Ws_bf, b_sout, Wr_bf, b_reward, Wc_bf, bc,
                     g_sn, b_sn, seq0_bf, fa_bf,
                     h0pool, h1pool, ubpool, uppool, cnt,
                     out_r, out_s);
}

// Round 4
// 1555.598 us; speedup vs baseline: 1.2891x; 1.2891x over previous
//
#include <hip/hip_runtime.h>
#include <cmath>

// Problem dims (fixed by the reference)
constexpr int kB = 32, kH = 48, kT = 24, kS = 256, kA = 64, kR = 8, kF = 1024;
constexpr int kSEQ = kH + 1;           // 49 = history + present step
constexpr float kEPS = 1e-5f;

// Persistent-kernel config: 128 blocks x 512 thr (8 waves).
// Blocks 0..63: layer-0 f-tiles (16 cols). Blocks 64..127: layer-1.
// Blocks 0..31 also run the fused head stage (one batch each).
constexpr int G  = 128;
constexpr int BT = 512;

// Tree barrier: 8 logical groups x 16 blocks, all counters at LLC.
constexpr int GRPS = 8;
constexpr int GMEM = 16;

typedef __attribute__((ext_vector_type(8))) short short8;   // 8 x bf16
typedef __attribute__((ext_vector_type(4))) float f32x4;

union U4S8 { uint4 u; short8 s; };

__device__ __forceinline__ unsigned bfbits(float x) {  // RNE f32->bf16
  unsigned u = __float_as_uint(x);
  return (u + 0x7fffu + ((u >> 16) & 1u)) >> 16;
}
__device__ __forceinline__ float bf_lo(unsigned u) { return __uint_as_float(u << 16); }
__device__ __forceinline__ float bf_hi(unsigned u) { return __uint_as_float(u & 0xffff0000u); }
__device__ __forceinline__ float bf2f(unsigned short h) {
  return __uint_as_float(((unsigned)h) << 16);
}
__device__ __forceinline__ float gelu_f(float x) {
  return 0.5f * x * (1.0f + erff(x * 0.7071067811865476f));
}
__device__ __forceinline__ float sigmoid_f(float x) {
  return 1.0f / (1.0f + expf(-x));
}

// sc1 (LLC write-through) store: makes produced data visible to all XCDs.
__device__ __forceinline__ void coh_st(unsigned* p, unsigned v) {
  __hip_atomic_store(p, v, __ATOMIC_RELAXED, __HIP_MEMORY_SCOPE_AGENT);
}

// Pinned LLC poll load: bypass L1+L2, explicit drain.
__device__ __forceinline__ unsigned poll_ld(const unsigned* p) {
  unsigned v;
  asm volatile("global_load_dword %0, %1, off sc0 sc1\n\t"
               "s_waitcnt vmcnt(0)"
               : "=v"(v) : "v"(p) : "memory");
  return v;
}

// ---------------- grid sync: two-level LLC tree (R10, measured win) --------
// arrival garr[g]: 16 RMWs/line; root: 8 RMW + pollers; release: 15 pollers.
__device__ __forceinline__ void sync_grid(unsigned* bar, int grp, int& t) {
  __syncthreads();
  if (threadIdx.x == 0) {
    const unsigned tt = (unsigned)t;
    unsigned* garr = bar + grp * 32;
    unsigned* root = bar + GRPS * 32;
    unsigned* grel = bar + (GRPS + 1) * 32 + grp * 32;
    const unsigned old = __hip_atomic_fetch_add(
        garr, 1u, __ATOMIC_RELAXED, __HIP_MEMORY_SCOPE_AGENT);
    if (old == (unsigned)GMEM * tt - 1u) {        // last local arriver
      const unsigned rold = __hip_atomic_fetch_add(
          root, 1u, __ATOMIC_RELAXED, __HIP_MEMORY_SCOPE_AGENT);
      if (rold != (unsigned)GRPS * tt - 1u) {
        while (poll_ld(root) < (unsigned)GRPS * tt) { }
      }
      __hip_atomic_fetch_add(grel, 1u, __ATOMIC_RELAXED,
                             __HIP_MEMORY_SCOPE_AGENT);
    } else {
      while (poll_ld(grel) < tt) { }
    }
  }
  __syncthreads();
  t++;
}

// ---------------- one GRU layer step via MFMA (R10-identical) --------------
// Block owns 16 f-cols of one layer. Wave wv = k-slice [wv*128, wv*128+128).
// B-frags (weights) resident in VGPRs. Sets: 0=r(i+h), 1=z(i+h), 2=n_i, 3=n_h.
// x/h inputs are PLAIN CACHED loads: every stage reads a buffer address never
// touched before in this launch (rotation) -> L2 must miss and fill from LLC.
__device__ __forceinline__ void layer_stage(
    const unsigned short* __restrict__ xsrc,   // [32][1024] bf16
    const unsigned short* __restrict__ hsrc,   // [32][1024] bf16
    unsigned short* __restrict__ hdst,         // [32][1024] bf16 (sc1 stores)
    const short8 (&Bf)[2][3][4],
    float bR, float bZ, float bIN, float bHN,
    float& h_old, float* part, int fb)
{
  const int tid = threadIdx.x;
  const int wv = tid >> 6, l = tid & 63, q = l >> 4, c = l & 15;

  short8 Afr[2][2][4];
  #pragma unroll
  for (int mt = 0; mt < 2; mt++)
    #pragma unroll
    for (int j = 0; j < 4; j++) {
      const int off = (mt*16 + c)*1024 + wv*128 + j*32 + q*8;
      Afr[0][mt][j] = *(const short8*)(xsrc + off);
      Afr[1][mt][j] = *(const short8*)(hsrc + off);
    }

  f32x4 C[4][2];
  #pragma unroll
  for (int s = 0; s < 4; s++)
    #pragma unroll
    for (int mt = 0; mt < 2; mt++)
      C[s][mt] = (f32x4){0.f, 0.f, 0.f, 0.f};

  #pragma unroll
  for (int mt = 0; mt < 2; mt++)
    #pragma unroll
    for (int j = 0; j < 4; j++) {
      C[0][mt] = __builtin_amdgcn_mfma_f32_16x16x32_bf16(Afr[0][mt][j], Bf[0][0][j], C[0][mt], 0, 0, 0);
      C[0][mt] = __builtin_amdgcn_mfma_f32_16x16x32_bf16(Afr[1][mt][j], Bf[1][0][j], C[0][mt], 0, 0, 0);
      C[1][mt] = __builtin_amdgcn_mfma_f32_16x16x32_bf16(Afr[0][mt][j], Bf[0][1][j], C[1][mt], 0, 0, 0);
      C[1][mt] = __builtin_amdgcn_mfma_f32_16x16x32_bf16(Afr[1][mt][j], Bf[1][1][j], C[1][mt], 0, 0, 0);
      C[2][mt] = __builtin_amdgcn_mfma_f32_16x16x32_bf16(Afr[0][mt][j], Bf[0][2][j], C[2][mt], 0, 0, 0);
      C[3][mt] = __builtin_amdgcn_mfma_f32_16x16x32_bf16(Afr[1][mt][j], Bf[1][2][j], C[3][mt], 0, 0, 0);
    }

  // k-slice partials -> LDS (swizzled: 2-way/bank over 64 lanes = free).
  const int perm = (wv + l + (l >> 3)) & 7;
  #pragma unroll
  for (int s = 0; s < 4; s++)
    #pragma unroll
    for (int mt = 0; mt < 2; mt++)
      #pragma unroll
      for (int r = 0; r < 4; r++)
        part[((s*2 + mt)*4 + r)*512 + l*8 + perm] = C[s][mt][r];
  __syncthreads();

  // combine: wave wv -> (mtile = wv&1, reg = wv>>1); lane -> one (b,f)
  const int mt_c = wv & 1, rg = wv >> 1;
  const int b_own = mt_c*16 + q*4 + rg;
  float S[4];
  #pragma unroll
  for (int s = 0; s < 4; s++) {
    const float* pp = part + ((s*2 + mt_c)*4 + rg)*512 + l*8;
    f32x4 a = *(const f32x4*)pp;
    f32x4 b = *(const f32x4*)(pp + 4);
    S[s] = ((a[0]+a[1]) + (a[2]+a[3])) + ((b[0]+b[1]) + (b[2]+b[3]));
  }
  float rr = sigmoid_f(S[0] + bR);
  float zz = sigmoid_f(S[1] + bZ);
  float nn = tanhf(S[2] + bIN + rr * (S[3] + bHN));
  float hn = (1.f - zz)*nn + zz*h_old;
  h_old = hn;
  float nb = __shfl_xor(hn, 1);
  if (!(c & 1)) {
    unsigned pk = bfbits(hn) | (bfbits(nb) << 16);
    coh_st((unsigned*)(hdst + b_own*1024 + fb*16 + c), pk);
  }
  __syncthreads();   // protect smem reuse by next stage
}

// ---------------- fused head + LN + pres + gelu (blocks 0..31, b=blk) ------
// R12: weight loads COALESCED via transposed layouts.
//   WsT2[(k>>1)*512 + j*2 + (k&1)] = W_sout[j][k]   (dword = k-pair for col j)
//   WstT[k*1024 + f]               = W_state[f][k]  (dword = (f0,f0+1) at k)
__device__ __forceinline__ void f3_stage(
    const unsigned short* __restrict__ y_bf, int t,
    const unsigned short* __restrict__ WsT2_bf, const float* __restrict__ b_sout,
    const unsigned short* __restrict__ Wr_bf, const float* __restrict__ b_reward,
    const unsigned short* __restrict__ WstT_bf, const float* __restrict__ b_state,
    const float* __restrict__ g_sn, const float* __restrict__ b_sn,
    const unsigned short* __restrict__ fa_bf,
    float* __restrict__ out_r, float* __restrict__ out_s,
    unsigned short* __restrict__ xbuf_bf, float* part, int b)
{
  const int tid = threadIdx.x;
  float* yb    = part;          // 1024: y in f32
  float* spart = part + 1024;   // 512
  float* s_sh  = part + 1536;   // 256
  float* rpart = part + 1792;   // 64
  float* red1  = part + 2048;   // 512
  float* red2  = part + 2560;   // 512

  {
    unsigned uu = *((const unsigned*)y_bf + b*512 + tid);   // cached (fresh buf)
    yb[tid*2]     = bf_lo(uu);
    yb[tid*2 + 1] = bf_hi(uu);
  }
  __syncthreads();
  {  // s partials: j = tid&255, k-half = tid>>8; coalesced dword loads
    const int j = tid & 255, ksh = tid >> 8;
    const unsigned* wp = (const unsigned*)WsT2_bf + (size_t)ksh*256*256 + j;
    const float* yp = yb + ksh*512;
    float acc = 0.f;
    #pragma unroll 8
    for (int kp = 0; kp < 256; kp++) {
      unsigned w = wp[kp*256];
      acc += bf_lo(w)*yp[2*kp] + bf_hi(w)*yp[2*kp + 1];
    }
    spart[tid] = acc;
  }
  __syncthreads();
  if (tid < 256) {
    float s = spart[tid] + spart[tid + 256] + b_sout[tid];
    out_s[((size_t)b*kT + t)*kS + tid] = s;
    s_sh[tid] = s;
  } else if (tid < 320) {
    const int idx = tid - 256, j = idx >> 3, ks = idx & 7;
    const unsigned short* wr = Wr_bf + j*1024 + ks*128;
    const float* yp = yb + ks*128;
    float acc = 0.f;
    #pragma unroll 4
    for (int k = 0; k < 128; k += 2) {
      unsigned w = *(const unsigned*)(wr + k);
      acc += bf_lo(w)*yp[k] + bf_hi(w)*yp[k+1];
    }
    rpart[idx] = acc;
  }
  __syncthreads();
  if (tid < 8) {
    float a = b_reward[tid];
    #pragma unroll
    for (int ks = 0; ks < 8; ks++) a += rpart[tid*8 + ks];
    out_r[((size_t)b*kT + t)*kR + tid] = tanhf(a);
  }
  if (t == kT - 1) return;   // uniform branch: last step needs no next-x
  __syncthreads();
  // u[f] = b_state[f] + W_state[f,:] @ s ; LN over 1024; x = gelu(LN + fa[t+1])
  const int f0 = tid*2;
  float a0 = b_state[f0], a1 = b_state[f0 + 1];
  {
    const unsigned* wp = (const unsigned*)WstT_bf + (f0 >> 1);
    #pragma unroll 8
    for (int k = 0; k < 256; k++) {
      unsigned w = wp[k*512];
      a0 += bf_lo(w)*s_sh[k];
      a1 += bf_hi(w)*s_sh[k];
    }
  }
  float s1 = a0 + a1, s2 = a0*a0 + a1*a1;
  red1[tid] = s1; red2[tid] = s2;
  __syncthreads();
  for (int off = 256; off > 0; off >>= 1) {
    if (tid < off) { red1[tid] += red1[tid + off]; red2[tid] += red2[tid + off]; }
    __syncthreads();
  }
  const float mean = red1[0] * (1.0f/kF);
  const float var  = red2[0] * (1.0f/kF) - mean*mean;
  const float inv  = rsqrtf(var + kEPS);
  unsigned fu = *((const unsigned*)(fa_bf + ((size_t)(t+1)*kB + b)*kF) + tid);
  float x0 = (a0 - mean)*inv*g_sn[f0]   + b_sn[f0]   + bf_lo(fu);
  float x1 = (a1 - mean)*inv*g_sn[f0+1] + b_sn[f0+1] + bf_hi(fu);
  unsigned pk = bfbits(gelu_f(x0)) | (bfbits(gelu_f(x1)) << 16);
  coh_st((unsigned*)xbuf_bf + b*512 + tid, pk);
}

// ---------------- B-fragment preamble (shared by both kernels) -------------
__device__ __forceinline__ void load_bfrags(
    const float* __restrict__ gru_Wi, const float* __restrict__ gru_Wh,
    int lay, int fb, int wv, int q, int c, short8 (&Bf)[2][3][4])
{
  const size_t WLL = (size_t)3 * kF * kF;
  const float* Wm[2] = { gru_Wi + lay*WLL, gru_Wh + lay*WLL };
  #pragma unroll
  for (int m = 0; m < 2; m++)
    #pragma unroll
    for (int g = 0; g < 3; g++)
      #pragma unroll
      for (int j = 0; j < 4; j++) {
        const float* p = Wm[m] + ((size_t)(g*kF + fb*16 + c))*kF + wv*128 + j*32 + q*8;
        float4 a = *(const float4*)p;
        float4 b = *(const float4*)(p + 4);
        U4S8 u;
        u.u.x = bfbits(a.x) | (bfbits(a.y) << 16);
        u.u.y = bfbits(a.z) | (bfbits(a.w) << 16);
        u.u.z = bfbits(b.x) | (bfbits(b.y) << 16);
        u.u.w = bfbits(b.z) | (bfbits(b.w) << 16);
        Bf[m][g][j] = u.s;
      }
}

// ---------------- persistent kernel 1: history wavefront -------------------
__global__ __launch_bounds__(BT, 2) void gru_hist(
    const float* __restrict__ gru_Wi, const float* __restrict__ gru_Wh,
    const float* __restrict__ gru_bi, const float* __restrict__ gru_bh,
    const unsigned short* __restrict__ seq0_bf,
    unsigned short* h0pool, unsigned short* h1pool,
    unsigned* cnt)
{
  __shared__ float part[32 * 512];   // 64 KB
  const int tid = threadIdx.x;
  const int blk = blockIdx.x;
  const int wv = tid >> 6, l = tid & 63, q = l >> 4, c = l & 15;
  const bool isL1 = (blk >= 64);
  const int fb = blk & 63;
  const int grp = blk >> 4;
  const int lay = isL1 ? 1 : 0;
  const size_t BF = (size_t)kB * kF;

  short8 Bf[2][3][4];
  load_bfrags(gru_Wi, gru_Wh, lay, fb, wv, q, c, Bf);
  const int f = fb*16 + c;
  const float* bi = gru_bi + lay*3*kF;
  const float* bh = gru_bh + lay*3*kF;
  const float bR  = bi[f] + bh[f];
  const float bZ  = bi[kF + f] + bh[kF + f];
  const float bIN = bi[2*kF + f];
  const float bHN = bh[2*kF + f];

  float h_old = 0.f;
  int tg = 1;

  #define H0P(i) (h0pool + (size_t)(i)*BF)
  #define H1P(i) (h1pool + (size_t)(i)*BF)
  // L0 at s (s<49): x=seq0[s],   h=h0p(s)   -> h0p(s+1)
  // L1 at s (s>=1): x=h0p(s),    h=h1p(s-1) -> h1p(s)
  for (int s = 0; s < 50; s++) {
    if (!isL1) {
      if (s < 49)
        layer_stage(seq0_bf + (size_t)s*BF, H0P(s), H0P(s+1),
                    Bf, bR, bZ, bIN, bHN, h_old, part, fb);
    } else {
      if (s >= 1)
        layer_stage(H0P(s), H1P(s-1), H1P(s),
                    Bf, bR, bZ, bIN, bHN, h_old, part, fb);
    }
    if (s < 49) sync_grid(cnt, grp, tg);   // last stage: kernel end syncs
  }
  #undef H0P
  #undef H1P
}

// ---------------- persistent kernel 2: future chain ------------------------
__global__ __launch_bounds__(BT, 2) void gru_fut(
    const float* __restrict__ gru_Wi, const float* __restrict__ gru_Wh,
    const float* __restrict__ gru_bi, const float* __restrict__ gru_bh,
    const unsigned short* __restrict__ WsT2_bf, const float* __restrict__ b_sout,
    const unsigned short* __restrict__ Wr_bf, const float* __restrict__ b_reward,
    const unsigned short* __restrict__ WstT_bf, const float* __restrict__ b_state,
    const float* __restrict__ g_sn, const float* __restrict__ b_sn,
    const unsigned short* __restrict__ fa_bf,
    unsigned short* h0pool, unsigned short* h1pool, unsigned short* xbpool,
    unsigned* cnt,
    float* __restrict__ out_r, float* __restrict__ out_s)
{
  __shared__ float part[32 * 512];   // 64 KB
  const int tid = threadIdx.x;
  const int blk = blockIdx.x;
  const int wv = tid >> 6, l = tid & 63, q = l >> 4, c = l & 15;
  const bool isL1 = (blk >= 64);
  const int fb = blk & 63;
  const int grp = blk >> 4;
  const int lay = isL1 ? 1 : 0;
  const size_t BF = (size_t)kB * kF;

  short8 Bf[2][3][4];
  load_bfrags(gru_Wi, gru_Wh, lay, fb, wv, q, c, Bf);
  const int f = fb*16 + c;
  const float* bi = gru_bi + lay*3*kF;
  const float* bh = gru_bh + lay*3*kF;
  const float bR  = bi[f] + bh[f];
  const float bZ  = bi[kF + f] + bh[kF + f];
  const float bIN = bi[2*kF + f];
  const float bHN = bh[2*kF + f];

  #define H0P(i) (h0pool + (size_t)(i)*BF)
  #define H1P(i) (h1pool + (size_t)(i)*BF)
  #define XBP(i) (xbpool + (size_t)(i)*BF)

  // h_old reload from pools (one bf16 rounding at the kernel boundary).
  const int b_own = (wv & 1)*16 + q*4 + (wv >> 1);
  float h_old;
  {
    const unsigned short* hs = isL1 ? H1P(49) : H0P(49);
    h_old = bf2f(hs[b_own*1024 + f]);
  }
  int tg = 1;

  // per t: F3 -> L0 -> L1 (serial feedback chain)
  // F3 at t: y=h1p(49+t), writes xbp(t) (t<23)
  // L0 at t: x=xbp(t), h=h0p(49+t) -> h0p(50+t)
  // L1 at t: x=h0p(50+t), h=h1p(49+t) -> h1p(50+t)
  for (int t = 0; t < kT; t++) {
    if (blk < kB)
      f3_stage(H1P(49+t), t, WsT2_bf, b_sout, Wr_bf, b_reward,
               WstT_bf, b_state, g_sn, b_sn, fa_bf,
               out_r, out_s, XBP(t), part, blk);
    if (t == kT - 1) break;
    sync_grid(cnt, grp, tg);
    if (!isL1)
      layer_stage(XBP(t), H0P(49+t), H0P(50+t),
                  Bf, bR, bZ, bIN, bHN, h_old, part, fb);
    sync_grid(cnt, grp, tg);
    if (isL1)
      layer_stage(H0P(50+t), H1P(49+t), H1P(50+t),
                  Bf, bR, bZ, bIN, bHN, h_old, part, fb);
    sync_grid(cnt, grp, tg);
  }
  #undef H0P
  #undef H1P
  #undef XBP
}

// ---------------- setup: convert + transpose head weights to bf16 ----------
__global__ __launch_bounds__(512) void convert_weights(
    const float* __restrict__ ws,  unsigned short* __restrict__ wsT2,
    const float* __restrict__ wst, unsigned short* __restrict__ wstT,
    const float* __restrict__ wr,  unsigned short* __restrict__ o3)
{
  const int stride = gridDim.x * blockDim.x;
  const int i0 = blockIdx.x * blockDim.x + threadIdx.x;
  // WsT2[(k>>1)*512 + j*2 + (k&1)] = bf16(W_sout[j][k]); j=i>>10, k=i&1023
  for (int i = i0; i < kS*kF; i += stride) {
    const int j = i >> 10, k = i & 1023;
    wsT2[(k >> 1)*512 + j*2 + (k & 1)] = (unsigned short)bfbits(ws[i]);
  }
  // WstT[k*1024 + f] = bf16(W_state[f][k]); f=i>>8, k=i&255
  for (int i = i0; i < kF*kS; i += stride) {
    const int ff = i >> 8, k = i & 255;
    wstT[k*1024 + ff] = (unsigned short)bfbits(wst[i]);
  }
  for (int i = i0; i < kR*kF; i += stride) o3[i] = (unsigned short)bfbits(wr[i]);
}

// ---------------- encoder: fa_bf[t][b][f] = bf16(LN(future_a@Wa^T+ba)*g+b) -
__global__ __launch_bounds__(256) void encode_fa_kernel(
    const float* __restrict__ future_a,
    const float* __restrict__ W_action, const float* __restrict__ b_action,
    const float* __restrict__ g_an, const float* __restrict__ b_an,
    unsigned short* __restrict__ fa_bf)
{
  __shared__ __align__(16) float arow[kA];
  __shared__ float red1[256], red2[256];
  const int bid = blockIdx.x;
  const int b = bid & (kB - 1);
  const int t = bid >> 5;
  const int tid = threadIdx.x;
  if (tid < kA) arow[tid] = future_a[((size_t)b*kT + t)*kA + tid];
  __syncthreads();
  float v[4]; float s1 = 0.f, s2 = 0.f;
  #pragma unroll
  for (int j = 0; j < 4; j++) {
    const int ff = tid + j*256;
    const float* wr = W_action + (size_t)ff*kA;
    float acc = b_action[ff];
    for (int k = 0; k < kA; k += 4) {
      float4 w  = *(const float4*)(wr + k);
      float4 xv = *(const float4*)(arow + k);
      acc += xv.x*w.x + xv.y*w.y + xv.z*w.z + xv.w*w.w;
    }
    v[j] = acc; s1 += acc; s2 += acc*acc;
  }
  red1[tid] = s1; red2[tid] = s2;
  __syncthreads();
  for (int off = 128; off > 0; off >>= 1) {
    if (tid < off) { red1[tid] += red1[tid+off]; red2[tid] += red2[tid+off]; }
    __syncthreads();
  }
  const float m = red1[0] * (1.0f/kF);
  const float va = red2[0] * (1.0f/kF) - m*m;
  const float inv = rsqrtf(va + kEPS);
  #pragma unroll
  for (int j = 0; j < 4; j++) {
    const int ff = tid + j*256;
    fa_bf[((size_t)t*kB + b)*kF + ff] =
        (unsigned short)bfbits((v[j] - m)*inv*g_an[ff] + b_an[ff]);
  }
}

// ---------------- encoder: seq0_bf = bf16(gelu(LN_s + LN_a)) ---------------
__global__ __launch_bounds__(256) void encode_seq0_kernel(
    const float* __restrict__ history_s, const float* __restrict__ history_a,
    const float* __restrict__ present_s,
    const float* __restrict__ W_state, const float* __restrict__ b_state,
    const float* __restrict__ g_sn, const float* __restrict__ b_sn,
    const float* __restrict__ W_action, const float* __restrict__ b_action,
    const float* __restrict__ g_an, const float* __restrict__ b_an,
    const unsigned short* __restrict__ fa_bf, unsigned short* __restrict__ seq0_bf)
{
  __shared__ __align__(16) float srow[kS];
  __shared__ __align__(16) float arow[kA];
  __shared__ float red1[256], red2[256];
  const int bid = blockIdx.x;
  const int b = bid & (kB - 1);
  const int t = bid >> 5;                 // 0..48
  const int tid = threadIdx.x;
  const bool hist = (t < kH);
  const float* sp = hist ? (history_s + ((size_t)b*kH + t)*kS)
                         : (present_s + (size_t)b*kS);
  srow[tid] = sp[tid];
  if (hist && tid < kA) arow[tid] = history_a[((size_t)b*kH + t)*kA + tid];
  __syncthreads();

  float u[4]; float s1 = 0.f, s2 = 0.f;
  #pragma unroll
  for (int j = 0; j < 4; j++) {
    const int ff = tid + j*256;
    const float* wr = W_state + (size_t)ff*kS;
    float acc = b_state[ff];
    for (int k = 0; k < kS; k += 4) {
      float4 w  = *(const float4*)(wr + k);
      float4 xv = *(const float4*)(srow + k);
      acc += xv.x*w.x + xv.y*w.y + xv.z*w.z + xv.w*w.w;
    }
    u[j] = acc; s1 += acc; s2 += acc*acc;
  }
  red1[tid] = s1; red2[tid] = s2;
  __syncthreads();
  for (int off = 128; off > 0; off >>= 1) {
    if (tid < off) { red1[tid] += red1[tid+off]; red2[tid] += red2[tid+off]; }
    __syncthreads();
  }
  const float mu = red1[0] * (1.0f/kF);
  const float vu = red2[0] * (1.0f/kF) - mu*mu;
  const float iu = rsqrtf(vu + kEPS);
  __syncthreads();

  if (hist) {
    float v[4]; s1 = 0.f; s2 = 0.f;
    #pragma unroll
    for (int j = 0; j < 4; j++) {
      const int ff = tid + j*256;
      const float* wr = W_action + (size_t)ff*kA;
      float acc = b_action[ff];
      for (int k = 0; k < kA; k += 4) {
        float4 w  = *(const float4*)(wr + k);
        float4 xv = *(const float4*)(arow + k);
        acc += xv.x*w.x + xv.y*w.y + xv.z*w.z + xv.w*w.w;
      }
      v[j] = acc; s1 += acc; s2 += acc*acc;
    }
    red1[tid] = s1; red2[tid] = s2;
    __syncthreads();
    for (int off = 128; off > 0; off >>= 1) {
      if (tid < off) { red1[tid] += red1[tid+off]; red2[tid] += red2[tid+off]; }
      __syncthreads();
    }
    const float mv = red1[0] * (1.0f/kF);
    const float vv = red2[0] * (1.0f/kF) - mv*mv;
    const float iv = rsqrtf(vv + kEPS);
    #pragma unroll
    for (int j = 0; j < 4; j++) {
      const int ff = tid + j*256;
      const float un = (u[j] - mu)*iu*g_sn[ff] + b_sn[ff];
      const float vn = (v[j] - mv)*iv*g_an[ff] + b_an[ff];
      seq0_bf[((size_t)t*kB + b)*kF + ff] = (unsigned short)bfbits(gelu_f(un + vn));
    }
  } else {
    #pragma unroll
    for (int j = 0; j < 4; j++) {
      const int ff = tid + j*256;
      const float un = (u[j] - mu)*iu*g_sn[ff] + b_sn[ff];
      seq0_bf[((size_t)t*kB + b)*kF + ff] =
          (unsigned short)bfbits(gelu_f(un + bf2f(fa_bf[(size_t)b*kF + ff])));
    }
  }
}

// ---------------- host launcher -------------------------------------------
extern "C" void kernel_launch(void* const* d_in, const int* in_sizes, int n_in,
                              void* d_out, int out_size, void* d_ws, size_t ws_size,
                              hipStream_t stream) {
  (void)in_sizes; (void)n_in; (void)out_size;
  const float* history_s = (const float*)d_in[0];
  const float* history_a = (const float*)d_in[1];
  const float* present_s = (const float*)d_in[2];
  /* d_in[3] future_s: unused by the reference forward */
  const float* future_a  = (const float*)d_in[4];
  const float* W_state   = (const float*)d_in[5];
  const float* b_state   = (const float*)d_in[6];
  const float* g_sn      = (const float*)d_in[7];
  const float* b_sn      = (const float*)d_in[8];
  const float* W_action  = (const float*)d_in[9];
  const float* b_action  = (const float*)d_in[10];
  const float* g_an      = (const float*)d_in[11];
  const float* b_an      = (const float*)d_in[12];
  const float* gru_Wi    = (const float*)d_in[13];
  const float* gru_Wh    = (const float*)d_in[14];
  const float* gru_bi    = (const float*)d_in[15];
  const float* gru_bh    = (const float*)d_in[16];
  const float* W_reward  = (const float*)d_in[17];
  const float* b_reward  = (const float*)d_in[18];
  const float* W_sout    = (const float*)d_in[19];
  const float* b_sout    = (const float*)d_in[20];

  // workspace layout (bytes, 16-aligned). Rotation pools: 73+73 h buffers
  // (64 KB each) + 23 xbuf. Two 2304-B barrier areas (hist, fut).
  char* ws = (char*)d_ws;
  unsigned short* seq0_bf = (unsigned short*)(ws + 0);            //  3,211,264
  unsigned short* fa_bf   = (unsigned short*)(ws + 3211264);      //  1,572,864
  unsigned short* WsT2_bf = (unsigned short*)(ws + 4784128);      //    524,288
  unsigned short* WstT_bf = (unsigned short*)(ws + 5308416);      //    524,288
  unsigned short* Wr_bf   = (unsigned short*)(ws + 5832704);      //     16,384
  unsigned short* h0pool  = (unsigned short*)(ws + 5849088);      //  4,784,128 (73 x 64K)
  unsigned short* h1pool  = (unsigned short*)(ws + 10633216);     //  4,784,128 (73 x 64K)
  unsigned short* xbpool  = (unsigned short*)(ws + 15417344);     //  1,507,328 (23 x 64K)
  unsigned*       cnt     = (unsigned*)(ws + 16924672);           //      4,608
  const size_t need = 16929280;
  if (ws_size < need) return;

  // Zero only: initial hidden buffers (index 0 of each pool) + barrier areas.
  hipMemsetAsync((void*)h0pool, 0, 65536, stream);
  hipMemsetAsync((void*)h1pool, 0, 65536, stream);
  hipMemsetAsync((void*)cnt, 0, 4608, stream);

  float* out_r = (float*)d_out;                          // [B][T][R]
  float* out_s = out_r + (size_t)kB*kT*kR;               // [B][T][S]

  hipLaunchKernelGGL(convert_weights, dim3(256), dim3(512), 0, stream,
                     W_sout, WsT2_bf, W_state, WstT_bf, W_reward, Wr_bf);
  hipLaunchKernelGGL(encode_fa_kernel, dim3(kT*kB), dim3(256), 0, stream,
                     future_a, W_action, b_action, g_an, b_an, fa_bf);
  hipLaunchKernelGGL(encode_seq0_kernel, dim3(kSEQ*kB), dim3(256), 0, stream,
                     history_s, history_a, present_s,
                     W_state, b_state, g_sn, b_sn,
                     W_action, b_action, g_an, b_an, fa_bf, seq0_bf);
  hipLaunchKernelGGL(gru_hist, dim3(G), dim3(BT), 0, stream,
                     gru_Wi, gru_Wh, gru_bi, gru_bh,
                     seq0_bf, h0pool, h1pool, cnt);
  hipLaunchKernelGGL(gru_fut, dim3(G), dim3(BT), 0, stream,
                     gru_Wi, gru_Wh, gru_bi, gru_bh,
                     WsT2_bf, b_sout, Wr_bf, b_reward, WstT_bf, b_state,
                     g_sn, b_sn, fa_bf,
                     h0pool, h1pool, xbpool, cnt + 576,
                     out_r, out_s);
}